// Round 1
// baseline (238.500 us; speedup 1.0000x reference)
//
#include <hip/hip_runtime.h>

// Spherical: out = x * |s|  (x: 8192x4096 fp32, s: scalar fp32)
// Pure streaming scale — memory-bound, zero reuse.
//
// R1 changes vs previous best (218.9 us):
//  - Drop the NONTEMPORAL hint on LOADS: input is 128 MiB (fits L3, likely
//    resident after the harness poison fill); nt-load defeats L3 hits.
//    Keep nt on STORES (output never re-read; don't evict the input).
//  - Grid-stride loop, grid capped at 2048 blocks (8 blocks/CU), 4x float4
//    unroll per iteration: 4 independent loads in flight per thread (ILP)
//    instead of 2, per G11 streaming guidance.

typedef float fvec4 __attribute__((ext_vector_type(4)));

__global__ __launch_bounds__(256) void spherical_scale_kernel(
    const fvec4* __restrict__ x4,
    const float* __restrict__ s_ptr,
    fvec4* __restrict__ out4,
    int n4)   // number of fvec4 elements
{
    const float s = fabsf(s_ptr[0]);
    const int stride = gridDim.x * blockDim.x;   // threads in grid
    int i = blockIdx.x * blockDim.x + threadIdx.x;

    // Main loop: 4 independent float4 loads in flight, then 4 nt stores.
    for (; i + 3 * stride < n4; i += 4 * stride) {
        fvec4 a = x4[i];
        fvec4 b = x4[i + stride];
        fvec4 c = x4[i + 2 * stride];
        fvec4 d = x4[i + 3 * stride];
        a *= s;
        b *= s;
        c *= s;
        d *= s;
        __builtin_nontemporal_store(a, &out4[i]);
        __builtin_nontemporal_store(b, &out4[i + stride]);
        __builtin_nontemporal_store(c, &out4[i + 2 * stride]);
        __builtin_nontemporal_store(d, &out4[i + 3 * stride]);
    }
    // Tail (no-op for 8192x4096: n4 = 8388608 divides evenly).
    for (; i < n4; i += stride) {
        fvec4 a = x4[i];
        a *= s;
        __builtin_nontemporal_store(a, &out4[i]);
    }
}

extern "C" void kernel_launch(void* const* d_in, const int* in_sizes, int n_in,
                              void* d_out, int out_size, void* d_ws, size_t ws_size,
                              hipStream_t stream) {
    const float* x = (const float*)d_in[0];
    const float* s = (const float*)d_in[1];
    float* out = (float*)d_out;

    const int n = in_sizes[0];        // 8192*4096 = 33554432 floats
    const int n4 = n / 4;             // 8388608 fvec4s
    const int block = 256;
    const int grid = 2048;            // 8 blocks/CU on 256 CUs; grid-stride

    spherical_scale_kernel<<<grid, block, 0, stream>>>(
        (const fvec4*)x, s, (fvec4*)out, n4);
}